// Round 12
// baseline (234.097 us; speedup 1.0000x reference)
//
#include <hip/hip_runtime.h>
#include <hip/hip_fp16.h>
#include <cstdint>
#include <cstddef>
#include <type_traits>

#define N_NODES 30000
#define N_EDGES 480000
#define IN_CH 128
#define HEADS1 5
#define C1 64
#define D1 (HEADS1 * C1) // 320
#define OUT_CH 64
#define PE_CNT 100000
#define NEG_SLOPE 0.2f
#define BCAP 64   // bucket: slot 0 = self-loop, slots 1..deg = edges (exact global ranks)
#define GEMM1_BLOCKS 469
#define GEMM2_BLOCKS 469
#define SG1_BLOCKS 64       // score-GEMM branch blocks (layer 1)
#define SG2_BLOCKS 64       // score-GEMM branch blocks (layer 2)
#define INIT_BLOCKS 120     // 512-thr init blocks
#define BB 60               // builder blocks (pass A / pass B), 512 thr each
#define EPB (N_EDGES / BB)  // 8000 edges per builder block (exact; u16 bins safe)
#define NW (N_NODES / 2)    // 15000 packed u32 words (2 x u16 bins per word)
#define PFX_BLOCKS 59       // prefix blocks: 59*256 = 15104 >= NW
#define OVF_CAP 65536       // overflow list capacity (writes clamped; p(use)~1e-18)
// R31: accept K2 ~47us floor (4 load-scheduling strategies all flat: 48.9 /
// 53.4 / 47.4 / 52.0; FETCH=150MB = 8-XCD x h1 compulsory, ~3.2TB/s L3 fill)
// -> revert gather to R28 compiler-batch form (best, 47.4). Pivot to the
// invisible ~158us:
//  (1) K1/K3 score epilogue = 160 shfl_xor + 160 adds per tile (~1000cy serial,
//      2.5x the tile's 80-MFMA work). Move scores to DEDICATED branch blocks:
//      as = x @ (W1^T att) as a tiny 16-col MFMA GEMM (numerics verified in
//      R29 — passed with identical absmax). Main GEMM keeps acc[20], sheds the
//      epilogue entirely (R29's mistake was acc[21] -> VGPR cliff).
//  (2) prefix: BB 120 -> 60 halves the serial block-scan length.
// Build scheme (R25-proven): two-pass counting sort, each edge visited exactly
// twice, zero global returning atomics (R19-R21: ~8/ns cap, 60us floor).

typedef _Float16 f16x8 __attribute__((ext_vector_type(8)));
typedef _Float16 f16x2 __attribute__((ext_vector_type(2)));
typedef float fx4 __attribute__((ext_vector_type(4)));

#if defined(__has_builtin)
#if __has_builtin(__builtin_amdgcn_fdot2)
#define HAS_FDOT2 1
#endif
#endif

static __device__ __forceinline__ float leaky(float x) {
    return fmaxf(x, NEG_SLOPE * x); // valid for 0<slope<1
}

// ---------------- barrier-free MFMA fp16 GEMM (h-output only, no score epilogue) ----------------
// Wave-slot per 16-row tile (30000 = 16*1875). No LDS, no barriers.
// mfma_f32_16x16x32_f16 layouts (HW-verified): A: lane holds A[m=lane&15][k=quad*8+j];
// B: lane holds B[k=quad*8+j][n=lane&15] (contiguous in Wt[n][k]); D: D[row=quad*4+reg][col=lane&15].
template<int NH, typename AT>
static __device__ __forceinline__ void gemm_phase(const AT* __restrict__ A,
                                                  const __half* __restrict__ Wt,
                                                  __half* __restrict__ C, int K,
                                                  int slot, int nsl, int lane) {
    const int N = NH * 64;
    int q = lane >> 4, l16 = lane & 15;
    for (int tile = slot; tile < N_NODES / 16; tile += nsl) {
        int rowBase = tile * 16;
        int arow = rowBase + l16;
        fx4 zero4 = {0.f, 0.f, 0.f, 0.f};
        fx4 acc[NH][4];
#pragma unroll
        for (int h = 0; h < NH; ++h)
#pragma unroll
            for (int c = 0; c < 4; ++c) acc[h][c] = zero4;
        for (int kk = 0; kk < K; kk += 32) {
            f16x8 af;
            if constexpr (std::is_same<AT, float>::value) {
                const float4* s = (const float4*)(A + (size_t)arow * K + kk + q * 8);
                float4 v0 = s[0], v1 = s[1];
                af[0] = (_Float16)v0.x; af[1] = (_Float16)v0.y;
                af[2] = (_Float16)v0.z; af[3] = (_Float16)v0.w;
                af[4] = (_Float16)v1.x; af[5] = (_Float16)v1.y;
                af[6] = (_Float16)v1.z; af[7] = (_Float16)v1.w;
            } else {
                af = *(const f16x8*)((const __half*)A + (size_t)arow * K + kk + q * 8);
            }
#pragma unroll
            for (int h = 0; h < NH; ++h) {
#pragma unroll
                for (int c = 0; c < 4; ++c) {
                    int col = h * 64 + c * 16 + l16;
                    f16x8 bf = *(const f16x8*)(Wt + (size_t)col * K + kk + q * 8);
                    acc[h][c] = __builtin_amdgcn_mfma_f32_16x16x32_f16(af, bf, acc[h][c], 0, 0, 0);
                }
            }
        }
#pragma unroll
        for (int h = 0; h < NH; ++h) {
#pragma unroll
            for (int c = 0; c < 4; ++c) {
                int gcol = h * 64 + c * 16 + l16;
#pragma unroll
                for (int reg = 0; reg < 4; ++reg) {
                    int grow = rowBase + q * 4 + reg;
                    C[(size_t)grow * N + gcol] = __float2half(acc[h][c][reg]);
                }
            }
        }
    }
}

// ---------------- R31: score GEMM — one 16-col group of projected att vectors ----------------
// as[n,h] = x[n,:]·(W @ att_h): B cols 0..NH-1 = src heads, 8..8+NH-1 = dst heads
// (zeros elsewhere). D: lane l16<NH writes as, 8<=l16<8+NH writes ad.
template<int SP, typename AT>
static __device__ __forceinline__ void score_gemm(const AT* __restrict__ A,
                                                  const __half* __restrict__ Wta, // [16][K]
                                                  int K,
                                                  float* __restrict__ as_out,
                                                  float* __restrict__ ad_out,
                                                  int slot, int nsl, int lane) {
    int q = lane >> 4, l16 = lane & 15;
    for (int tile = slot; tile < N_NODES / 16; tile += nsl) {
        int rowBase = tile * 16;
        int arow = rowBase + l16;
        fx4 acc = {0.f, 0.f, 0.f, 0.f};
        for (int kk = 0; kk < K; kk += 32) {
            f16x8 af;
            if constexpr (std::is_same<AT, float>::value) {
                const float4* s = (const float4*)(A + (size_t)arow * K + kk + q * 8);
                float4 v0 = s[0], v1 = s[1];
                af[0] = (_Float16)v0.x; af[1] = (_Float16)v0.y;
                af[2] = (_Float16)v0.z; af[3] = (_Float16)v0.w;
                af[4] = (_Float16)v1.x; af[5] = (_Float16)v1.y;
                af[6] = (_Float16)v1.z; af[7] = (_Float16)v1.w;
            } else {
                af = *(const f16x8*)((const __half*)A + (size_t)arow * K + kk + q * 8);
            }
            f16x8 bf = *(const f16x8*)(Wta + (size_t)l16 * K + kk + q * 8);
            acc = __builtin_amdgcn_mfma_f32_16x16x32_f16(af, bf, acc, 0, 0, 0);
        }
#pragma unroll
        for (int reg = 0; reg < 4; ++reg) {
            int grow = rowBase + q * 4 + reg;
            if constexpr (SP == 8) {
                if (l16 < HEADS1) as_out[(size_t)grow * 8 + l16] = acc[reg];
                else if (l16 >= 8 && l16 < 8 + HEADS1) ad_out[(size_t)grow * 8 + (l16 - 8)] = acc[reg];
            } else {
                if (l16 == 0) as_out[grow] = acc[reg];
                else if (l16 == 8) ad_out[grow] = acc[reg];
            }
        }
    }
}

// ================ K0 (512-thr): init (self-loops, weight transpose, att projection) || pass A histogram ================
__global__ __launch_bounds__(512) void k_init(int* __restrict__ ovfc,
                                              int* __restrict__ esrc2,
                                              const float* __restrict__ W1,
                                              __half* __restrict__ Wt1,
                                              const float* __restrict__ W2,
                                              __half* __restrict__ Wt2,
                                              __half* __restrict__ Wt1a, // [16][128]
                                              __half* __restrict__ Wt2a, // [16][320]
                                              const float* __restrict__ att_src1,
                                              const float* __restrict__ att_dst1,
                                              const float* __restrict__ att_src2,
                                              const float* __restrict__ att_dst2,
                                              const int* __restrict__ edge,
                                              unsigned* __restrict__ partA) {
    __shared__ unsigned bins[NW]; // 60000 B
    if (blockIdx.x < INIT_BLOCKS) {
        int t = blockIdx.x * 512 + threadIdx.x;
        int nthr = INIT_BLOCKS * 512; // 61440
        for (int i = t; i < N_NODES; i += nthr) esrc2[i * BCAP] = i; // self-loop = slot 0
        if (t == 0) *ovfc = 0;
        const int T1 = IN_CH * D1, T2 = D1 * OUT_CH; // 40960 + 20480 = 61440
        for (int idx = t; idx < T1 + T2; idx += nthr) {
            if (idx < T1) {
                int k = idx / D1, n = idx - k * D1;
                Wt1[(size_t)n * IN_CH + k] = __float2half(W1[idx]);
            } else {
                int i2 = idx - T1;
                int k = i2 / OUT_CH, n = i2 - k * OUT_CH;
                Wt2[(size_t)n * D1 + k] = __float2half(W2[i2]);
            }
        }
        // projected att vectors (R29-verified math): w[h][k] = sum_c W[k][h*64+c]*att[h*64+c]
        for (int i = t; i < 1280; i += nthr) { // 128 k x (5 src + 5 dst)
            int k = i / 10, v = i - k * 10;
            int h = (v >= 5) ? v - 5 : v;
            const float* att = (v >= 5) ? att_dst1 : att_src1;
            float a = 0.f;
#pragma unroll 8
            for (int c = 0; c < 64; ++c)
                a += W1[(size_t)k * D1 + h * 64 + c] * att[h * 64 + c];
            int col = ((v >= 5) ? 8 : 0) + h;
            Wt1a[(size_t)col * IN_CH + k] = __float2half(a);
        }
        for (int i = t; i < 768; i += nthr) { // zero unused cols {5,6,7,13,14,15}
            int c6 = i >> 7, k = i & 127;
            int col = (c6 < 3) ? (5 + c6) : (10 + c6);
            Wt1a[(size_t)col * IN_CH + k] = __half(0);
        }
        for (int i = t; i < 640; i += nthr) { // 320 k x (src,dst) for layer 2
            int k = i >> 1, v = i & 1;
            const float* att = v ? att_dst2 : att_src2;
            float a = 0.f;
#pragma unroll 8
            for (int c = 0; c < 64; ++c)
                a += W2[(size_t)k * OUT_CH + c] * att[c];
            int col = v * 8;
            Wt2a[(size_t)col * D1 + k] = __float2half(a);
        }
        for (int i = t; i < 4480; i += nthr) { // zero unused cols {1..7, 9..15}
            int c14 = i / 320, k = i - c14 * 320;
            int col = (c14 < 7) ? (1 + c14) : (2 + c14);
            Wt2a[(size_t)col * D1 + k] = __half(0);
        }
    } else {
        int b = blockIdx.x - INIT_BLOCKS; // 0..BB-1
        for (int i = threadIdx.x; i < NW; i += 512) bins[i] = 0;
        __syncthreads();
        int e0 = b * EPB;
        for (int e = e0 + ((int)threadIdx.x << 2); e < e0 + EPB; e += 2048) {
            int4 dd = *(const int4*)(edge + N_EDGES + e);
            atomicAdd(&bins[dd.x >> 1], (dd.x & 1) ? 65536u : 1u);
            atomicAdd(&bins[dd.y >> 1], (dd.y & 1) ? 65536u : 1u);
            atomicAdd(&bins[dd.z >> 1], (dd.z & 1) ? 65536u : 1u);
            atomicAdd(&bins[dd.w >> 1], (dd.w & 1) ? 65536u : 1u);
        }
        __syncthreads();
        for (int i = threadIdx.x; i < NW; i += 512)
            partA[(size_t)b * NW + i] = bins[i];
    }
}

// ================ K1: layer-1 GEMM || prefix || score-GEMM ================
__global__ __launch_bounds__(256) void k_build_gemm1(const unsigned* __restrict__ partA,
                                                     unsigned* __restrict__ offA,
                                                     int* __restrict__ cnt,
                                                     const float* __restrict__ x,
                                                     const __half* __restrict__ Wt1,
                                                     const __half* __restrict__ Wt1a,
                                                     __half* __restrict__ h1,
                                                     float* __restrict__ as1,
                                                     float* __restrict__ ad1) {
    int lane = threadIdx.x & 63, wv = threadIdx.x >> 6;
    if (blockIdx.x < GEMM1_BLOCKS) {
        gemm_phase<HEADS1, float>(x, Wt1, h1, IN_CH,
                                  blockIdx.x * 4 + wv, GEMM1_BLOCKS * 4, lane);
    } else if (blockIdx.x < GEMM1_BLOCKS + PFX_BLOCKS) {
        int w = (blockIdx.x - GEMM1_BLOCKS) * 256 + threadIdx.x;
        if (w < NW) {
            unsigned s0 = 1, s1 = 1; // slot 0 = self-loop
            for (int b0 = 0; b0 < BB; b0 += 10) {
                unsigned v[10];
#pragma unroll
                for (int u = 0; u < 10; ++u)
                    v[u] = partA[(size_t)(b0 + u) * NW + w];
#pragma unroll
                for (int u = 0; u < 10; ++u) {
                    offA[(size_t)(b0 + u) * NW + w] = min(s0, 64u) | (min(s1, 64u) << 16);
                    s0 += v[u] & 0xFFFFu;
                    s1 += v[u] >> 16;
                }
            }
            cnt[2 * w] = (int)s0;
            cnt[2 * w + 1] = (int)s1;
        }
    } else {
        int sb = blockIdx.x - GEMM1_BLOCKS - PFX_BLOCKS;
        score_gemm<8, float>(x, Wt1a, IN_CH, as1, ad1,
                             sb * 4 + wv, SG1_BLOCKS * 4, lane);
    }
}

// ================ K1.5 (512-thr): pass B — rank + scatter (all lanes active) ================
__global__ __launch_bounds__(512) void k_rank(const int* __restrict__ edge,
                                              const unsigned* __restrict__ offA,
                                              int* __restrict__ esrc2,
                                              int* __restrict__ ovf_cnt,
                                              int* __restrict__ ovf) {
    __shared__ unsigned bins[NW];
    int b = blockIdx.x;
    for (int i = threadIdx.x; i < NW; i += 512) bins[i] = 0;
    __syncthreads();
    int e0 = b * EPB;
    for (int e = e0 + ((int)threadIdx.x << 2); e < e0 + EPB; e += 2048) {
        int4 dd = *(const int4*)(edge + N_EDGES + e);
        int4 ss = *(const int4*)(edge + e);
        int dv[4] = {dd.x, dd.y, dd.z, dd.w};
        int sv[4] = {ss.x, ss.y, ss.z, ss.w};
#pragma unroll
        for (int u = 0; u < 4; ++u) {
            int d = dv[u];
            unsigned ret = atomicAdd(&bins[d >> 1], (d & 1) ? 65536u : 1u);
            unsigned lr = (d & 1) ? (ret >> 16) : (ret & 0xFFFFu);
            unsigned off = offA[(size_t)b * NW + (d >> 1)];
            off = (d & 1) ? (off >> 16) : (off & 0xFFFFu);
            unsigned slot = off + lr;
            if (slot < BCAP) {
                esrc2[(d << 6) + slot] = sv[u];
            } else { // true global rank >= 64 (off clamped at 64 keeps this exact)
                int oi = atomicAdd(ovf_cnt, 1);
                if (oi < OVF_CAP) { ovf[2 * oi] = d; ovf[2 * oi + 1] = sv[u]; }
            }
        }
    }
}

// ---------------- R28 gather (best measured): all-heads-upfront, compiler-scheduled ----------------
template<int NH, int NS, bool RELU>
static __device__ __forceinline__ void gather_all(const __half* __restrict__ base, // hf + cg*8
                                                  const unsigned (&wpkw)[NH][64],
                                                  const int (&jbufw)[64],
                                                  float (&redw)[584],
                                                  const float* __restrict__ bias,
                                                  __half* __restrict__ zrow, // zout + node*RS
                                                  int es, int cg, int lane) {
    int kA = es, kB = es + 8, kC = es + 16, kD = es + 24;
    int jA = jbufw[kA], jB = jbufw[kB];
    int jC = (NS == 4) ? jbufw[kC] : 0;
    int jD = (NS == 4) ? jbufw[kD] : 0;
    float4 v[NH][4];
#pragma unroll
    for (int h = 0; h < NH; ++h) {
        const __half* hb = base + h * 64;
        v[h][0] = *(const float4*)(hb + jA);
        v[h][1] = *(const float4*)(hb + jB);
        if (NS == 4) {
            v[h][2] = *(const float4*)(hb + jC);
            v[h][3] = *(const float4*)(hb + jD);
        }
    }
#pragma unroll
    for (int h = 0; h < NH; ++h) {
        unsigned uA = wpkw[h][kA], uB = wpkw[h][kB];
        __half2 hwA = *(__half2*)&uA, hwB = *(__half2*)&uB;
        const __half2* pA = (const __half2*)&v[h][0];
        const __half2* pB = (const __half2*)&v[h][1];
        __half2 a2[4] = {__half2{0, 0}, __half2{0, 0}, __half2{0, 0}, __half2{0, 0}};
#pragma unroll
        for (int i = 0; i < 4; ++i) {
            a2[i] = __hfma2(pA[i], hwA, a2[i]);
            a2[i] = __hfma2(pB[i], hwB, a2[i]);
        }
        if (NS == 4) {
            unsigned uC = wpkw[h][kC], uD = wpkw[h][kD];
            __half2 hwC = *(__half2*)&uC, hwD = *(__half2*)&uD;
            const __half2* pC = (const __half2*)&v[h][2];
            const __half2* pD = (const __half2*)&v[h][3];
#pragma unroll
            for (int i = 0; i < 4; ++i) {
                a2[i] = __hfma2(pC[i], hwC, a2[i]);
                a2[i] = __hfma2(pD[i], hwD, a2[i]);
            }
        }
        // epilogue for head h: fp32 cross-es reduce via LDS pad-9 transpose
#pragma unroll
        for (int i = 0; i < 4; ++i) {
            float2 f = __half22float2(a2[i]);
            redw[(cg * 8 + 2 * i) * 9 + es] = f.x;
            redw[(cg * 8 + 2 * i + 1) * 9 + es] = f.y;
        }
        float tot = 0.f;
#pragma unroll
        for (int e2 = 0; e2 < 8; ++e2)
            tot += redw[lane * 9 + e2];
        float o = tot + bias[h * 64 + lane];
        if (RELU) o = fmaxf(o, 0.f);
        zrow[h * 64 + lane] = __float2half(o);
    }
}

// ================ head-merged softmax + aggregate — ONE WAVE PER NODE ================
template<int NH, bool RELU>
__global__ __launch_bounds__(256) void k_attn_agg(const int* __restrict__ cnt,
                                                  const int* __restrict__ esrc2,
                                                  const int* __restrict__ ovf_cnt,
                                                  const int* __restrict__ ovf,
                                                  const __half* __restrict__ hf,   // [N][NH*64]
                                                  const float* __restrict__ a_src, // [N][SP]
                                                  const float* __restrict__ a_dst, // [N][SP]
                                                  const float* __restrict__ bias,  // [NH*64]
                                                  __half* __restrict__ zout) {     // [N][NH*64]
    const int SP = (NH == 1) ? 1 : 8;
    __shared__ unsigned wpk[4][NH][64];
    __shared__ int jbuf[4][64];
    __shared__ float red[4][584];
    int node = (blockIdx.x * 256 + threadIdx.x) >> 6;
    int lane = threadIdx.x & 63;
    int wv = threadIdx.x >> 6;
    if (node >= N_NODES) return;
    int deg = cnt[node];
    const int RS = NH * 64;
    // dst-scores for this node (wave-uniform broadcast loads)
    float da[NH];
    if constexpr (NH == 1) {
        da[0] = a_dst[node];
    } else {
        float4 d0 = *(const float4*)(a_dst + (size_t)node * SP);
        da[0] = d0.x; da[1] = d0.y; da[2] = d0.z; da[3] = d0.w;
        da[4] = a_dst[(size_t)node * SP + 4];
    }
    if (deg <= BCAP) {
        int es = lane >> 3, cg = lane & 7;
        int joff = 0;
        float e[NH];
#pragma unroll
        for (int h = 0; h < NH; ++h) e[h] = 0.f;
        if (lane < deg) {
            int j = esrc2[node * BCAP + lane];
            joff = j * RS;
            if constexpr (NH == 1) {
                e[0] = __expf(leaky(a_src[j] + da[0]));
            } else {
                float4 s0 = *(const float4*)(a_src + (size_t)j * SP);
                float s4 = a_src[(size_t)j * SP + 4];
                e[0] = __expf(leaky(s0.x + da[0]));
                e[1] = __expf(leaky(s0.y + da[1]));
                e[2] = __expf(leaky(s0.z + da[2]));
                e[3] = __expf(leaky(s0.w + da[3]));
                e[4] = __expf(leaky(s4 + da[4]));
            }
        }
        float s[NH];
#pragma unroll
        for (int h = 0; h < NH; ++h) s[h] = e[h];
#pragma unroll
        for (int off = 1; off < 64; off <<= 1) {
#pragma unroll
            for (int h = 0; h < NH; ++h) s[h] += __shfl_xor(s[h], off, 64);
        }
#pragma unroll
        for (int h = 0; h < NH; ++h) {
            float r = 1.f / (s[h] + 1e-16f);
            __half2 wn = __float2half2_rn(e[h] * r);
            wpk[wv][h][lane] = *(unsigned*)&wn;
        }
        jbuf[wv][lane] = joff;
        const __half* base = hf + cg * 8;
        __half* zrow = zout + (size_t)node * RS;
        if (deg <= 16) {
            gather_all<NH, 2, RELU>(base, wpk[wv], jbuf[wv], red[wv], bias, zrow, es, cg, lane);
        } else if (deg <= 32) {
            gather_all<NH, 4, RELU>(base, wpk[wv], jbuf[wv], red[wv], bias, zrow, es, cg, lane);
        } else {
            // legacy serial path (deg in (32,64], ~0.04% of nodes)
#pragma unroll
            for (int h = 0; h < NH; ++h) {
                const __half* hbase = hf + h * 64 + cg * 8;
                __half2 acch[4] = {__half2{0, 0}, __half2{0, 0}, __half2{0, 0}, __half2{0, 0}};
                for (int k0 = 0; k0 < deg; k0 += 32) {
                    int kA = k0 + es, kB = kA + 8, kC = kA + 16, kD = kA + 24;
                    unsigned uA = wpk[wv][h][kA];
                    unsigned uB = wpk[wv][h][kB];
                    unsigned uC = wpk[wv][h][kC];
                    unsigned uD = wpk[wv][h][kD];
                    int jA = jbuf[wv][kA];
                    int jB = jbuf[wv][kB];
                    int jC = jbuf[wv][kC];
                    int jD = jbuf[wv][kD];
                    float4 vA = *(const float4*)(hbase + jA);
                    float4 vB = *(const float4*)(hbase + jB);
                    float4 vC = *(const float4*)(hbase + jC);
                    float4 vD = *(const float4*)(hbase + jD);
                    __half2 hwA = *(__half2*)&uA, hwB = *(__half2*)&uB;
                    __half2 hwC = *(__half2*)&uC, hwD = *(__half2*)&uD;
                    const __half2* pA = (const __half2*)&vA;
                    const __half2* pB = (const __half2*)&vB;
                    const __half2* pC = (const __half2*)&vC;
                    const __half2* pD = (const __half2*)&vD;
#pragma unroll
                    for (int i = 0; i < 4; ++i) {
                        acch[i] = __hfma2(pA[i], hwA, acch[i]);
                        acch[i] = __hfma2(pB[i], hwB, acch[i]);
                        acch[i] = __hfma2(pC[i], hwC, acch[i]);
                        acch[i] = __hfma2(pD[i], hwD, acch[i]);
                    }
                }
#pragma unroll
                for (int i = 0; i < 4; ++i) {
                    float2 f = __half22float2(acch[i]);
                    red[wv][(cg * 8 + 2 * i) * 9 + es] = f.x;
                    red[wv][(cg * 8 + 2 * i + 1) * 9 + es] = f.y;
                }
                float tot = 0.f;
#pragma unroll
                for (int e2 = 0; e2 < 8; ++e2)
                    tot += red[wv][lane * 9 + e2];
                float o = tot + bias[h * 64 + lane];
                if (RELU) o = fmaxf(o, 0.f);
                zrow[h * 64 + lane] = __float2half(o);
            }
        }
    } else {
        // cold path: deg > BCAP. lane = channel; bucket (64 full) + overflow scan.
        int ovn = min(*ovf_cnt, OVF_CAP);
#pragma unroll
        for (int h = 0; h < NH; ++h) {
            float adsth = da[h];
            float sden = __expf(leaky(a_src[(size_t)esrc2[node * BCAP + lane] * SP + h] + adsth));
#pragma unroll
            for (int off = 1; off < 64; off <<= 1)
                sden += __shfl_xor(sden, off, 64);
            float s2 = 0.f;
            for (int k = lane; k < ovn; k += 64)
                if (ovf[2 * k] == node)
                    s2 += __expf(leaky(a_src[(size_t)ovf[2 * k + 1] * SP + h] + adsth));
#pragma unroll
            for (int off = 1; off < 64; off <<= 1)
                s2 += __shfl_xor(s2, off, 64);
            float r = 1.f / (sden + s2 + 1e-16f);
            float a = 0.f;
            for (int k = 0; k < BCAP; ++k) {
                int j = esrc2[node * BCAP + k];
                float w = __expf(leaky(a_src[(size_t)j * SP + h] + adsth));
                a += w * __half2float(hf[(size_t)j * RS + h * 64 + lane]);
            }
            for (int k = 0; k < ovn; ++k) {
                if (ovf[2 * k] == node) {
                    int j = ovf[2 * k + 1];
                    float w = __expf(leaky(a_src[(size_t)j * SP + h] + adsth));
                    a += w * __half2float(hf[(size_t)j * RS + h * 64 + lane]);
                }
            }
            float o = a * r + bias[h * 64 + lane];
            if (RELU) o = fmaxf(o, 0.f);
            zout[(size_t)node * RS + h * 64 + lane] = __float2half(o);
        }
    }
}

// ================ K3: layer-2 GEMM || score-GEMM ================
__global__ __launch_bounds__(256) void k_gemm2(const __half* __restrict__ z1,
                                               const __half* __restrict__ Wt2,
                                               const __half* __restrict__ Wt2a,
                                               __half* __restrict__ h2,
                                               float* __restrict__ as2,
                                               float* __restrict__ ad2) {
    int lane = threadIdx.x & 63, wv = threadIdx.x >> 6;
    if (blockIdx.x < GEMM2_BLOCKS) {
        gemm_phase<1, __half>(z1, Wt2, h2, D1,
                              blockIdx.x * 4 + wv, GEMM2_BLOCKS * 4, lane);
    } else {
        int sb = blockIdx.x - GEMM2_BLOCKS;
        score_gemm<1, __half>(z1, Wt2a, D1, as2, ad2,
                              sb * 4 + wv, SG2_BLOCKS * 4, lane);
    }
}

// ================ decode: 8 lanes per edge, 16B fp16 loads, fdot2 ================
__global__ __launch_bounds__(256) void k_decode(const int* __restrict__ pos,
                                                const int* __restrict__ neg,
                                                const __half* __restrict__ z2,
                                                float* __restrict__ out) {
    int t = blockIdx.x * 256 + threadIdx.x;
    int e = t >> 3;
    int lc = t & 7;
    if (e >= 2 * PE_CNT) return;
    int a, b;
    if (e < PE_CNT) { a = pos[e]; b = pos[PE_CNT + e]; }
    else { int k = e - PE_CNT; a = neg[k]; b = neg[PE_CNT + k]; }
    union U { float4 f; f16x2 h[4]; __half2 hh[4]; } ua, ub;
    ua.f = *(const float4*)(z2 + (size_t)a * OUT_CH + lc * 8);
    ub.f = *(const float4*)(z2 + (size_t)b * OUT_CH + lc * 8);
    float v = 0.f;
#pragma unroll
    for (int i = 0; i < 4; ++i) {
#ifdef HAS_FDOT2
        v = __builtin_amdgcn_fdot2(ua.h[i], ub.h[i], v, false);
#else
        float2 fa = __half22float2(ua.hh[i]);
        float2 fb = __half22float2(ub.hh[i]);
        v += fa.x * fb.x + fa.y * fb.y;
#endif
    }
#pragma unroll
    for (int off = 1; off < 8; off <<= 1)
        v += __shfl_xor(v, off, 64);
    if (lc == 0) out[e] = v;
}

extern "C" void kernel_launch(void* const* d_in, const int* in_sizes, int n_in,
                              void* d_out, int out_size, void* d_ws, size_t ws_size,
                              hipStream_t stream) {
    const float* x        = (const float*)d_in[0];
    const int* edge_index = (const int*)d_in[1];
    const int* pos_ei     = (const int*)d_in[2];
    const int* neg_ei     = (const int*)d_in[3];
    const float* W1       = (const float*)d_in[4];
    const float* att_src1 = (const float*)d_in[5];
    const float* att_dst1 = (const float*)d_in[6];
    const float* b1       = (const float*)d_in[7];
    const float* W2       = (const float*)d_in[8];
    const float* att_src2 = (const float*)d_in[9];
    const float* att_dst2 = (const float*)d_in[10];
    const float* b2       = (const float*)d_in[11];
    float* out            = (float*)d_out;

    char* ws = (char*)d_ws;
    size_t off = 0;
    auto alloc = [&](size_t bytes) -> void* {
        void* p = ws + off;
        off = (off + bytes + 255) & ~(size_t)255;
        return p;
    };
    int* cnt     = (int*)alloc(sizeof(int) * N_NODES);
    int* ovfc    = (int*)alloc(sizeof(int) * 8);
    int* esrc2   = (int*)alloc(sizeof(int) * (size_t)N_NODES * BCAP);
    int* ovf     = (int*)alloc(sizeof(int) * (size_t)2 * OVF_CAP); // 512KB capped
    __half* h1   = (__half*)alloc(sizeof(__half) * (size_t)N_NODES * D1);
    __half* z1   = (__half*)alloc(sizeof(__half) * (size_t)N_NODES * D1);
    __half* h2   = (__half*)alloc(sizeof(__half) * (size_t)N_NODES * OUT_CH);
    __half* z2   = (__half*)alloc(sizeof(__half) * (size_t)N_NODES * OUT_CH);
    __half* Wt1  = (__half*)alloc(sizeof(__half) * (size_t)D1 * IN_CH);
    __half* Wt2  = (__half*)alloc(sizeof(__half) * (size_t)OUT_CH * D1);
    __half* Wt1a = (__half*)alloc(sizeof(__half) * (size_t)16 * IN_CH);
    __half* Wt2a = (__half*)alloc(sizeof(__half) * (size_t)16 * D1);
    float* as1   = (float*)alloc(sizeof(float) * (size_t)N_NODES * 8); // [N][8] node-major, 5 used
    float* ad1   = (float*)alloc(sizeof(float) * (size_t)N_NODES * 8); // [N][8]
    float* as2   = (float*)alloc(sizeof(float) * (size_t)N_NODES);
    float* ad2   = (float*)alloc(sizeof(float) * (size_t)N_NODES);
    // partA/offA (3.6MB each at BB=60) ALIAS z1's 19.2MB: both dead after k_rank,
    // and z1 is first written in K2 which stream-orders after k_rank.
    unsigned* partA = (unsigned*)z1;
    unsigned* offA  = (unsigned*)((char*)z1 + (size_t)BB * NW * sizeof(unsigned));

    // K0: init (self-loops, weight prep, att projection) || pass A (LDS histogram -> partA)
    k_init<<<INIT_BLOCKS + BB, 512, 0, stream>>>(ovfc, esrc2, W1, Wt1, W2, Wt2,
                                                 Wt1a, Wt2a,
                                                 att_src1, att_dst1, att_src2, att_dst2,
                                                 edge_index, partA);
    // K1: layer-1 MFMA GEMM || prefix (partA -> offA, cnt) || score-GEMM (as1/ad1)
    k_build_gemm1<<<GEMM1_BLOCKS + PFX_BLOCKS + SG1_BLOCKS, 256, 0, stream>>>(
        partA, offA, cnt, x, Wt1, Wt1a, h1, as1, ad1);
    // K1.5: pass B — rank assignment + esrc2 scatter
    k_rank<<<BB, 512, 0, stream>>>(edge_index, offA, esrc2, ovfc, ovf);
    // K2: layer-1 softmax-aggregate (+relu) — one wave per node, 5 heads merged
    k_attn_agg<HEADS1, true><<<(N_NODES + 3) / 4, 256, 0, stream>>>(
        cnt, esrc2, ovfc, ovf, h1, as1, ad1, b1, z1);
    // K3: layer-2 GEMM || score-GEMM (as2/ad2)
    k_gemm2<<<GEMM2_BLOCKS + SG2_BLOCKS, 256, 0, stream>>>(z1, Wt2, Wt2a, h2, as2, ad2);
    // K4: layer-2 softmax-aggregate
    k_attn_agg<1, false><<<(N_NODES + 3) / 4, 256, 0, stream>>>(
        cnt, esrc2, ovfc, ovf, h2, as2, ad2, b2, z2);
    // K5: decode
    k_decode<<<(2 * PE_CNT * 8 + 255) / 256, 256, 0, stream>>>(pos_ei, neg_ei, z2, out);

    (void)in_sizes; (void)n_in; (void)out_size; (void)ws_size;
}

// Round 14
// 204.727 us; speedup vs baseline: 1.1435x; 1.1435x over previous
//
#include <hip/hip_runtime.h>
#include <hip/hip_fp16.h>
#include <cstdint>
#include <cstddef>
#include <type_traits>

#define N_NODES 30000
#define N_EDGES 480000
#define N_EDGES_SL (N_EDGES + N_NODES) // 510000
#define IN_CH 128
#define HEADS1 5
#define C1 64
#define D1 (HEADS1 * C1) // 320
#define OUT_CH 64
#define PE_CNT 100000
#define NEG_SLOPE 0.2f
#define BCAP 64   // bucket: slot 0 = self-loop, slots 1..deg = edges (exact global ranks)
#define GEMM1_BLOCKS 469
#define INIT_BLOCKS 120     // 512-thr init blocks
#define BB 120              // builder blocks (pass A / pass B), 512 thr each
#define EPB (N_EDGES / BB)  // 4000 edges per builder block (exact)
#define NW (N_NODES / 2)    // 15000 packed u32 words (2 x u16 bins per word)
#define PFX_BLOCKS 59       // prefix blocks: 59*256 = 15104 >= NW
#define OVF_CAP 65536       // overflow list capacity (writes clamped; p(use)~1e-18)
// R33 = RESUBMIT of the measured-best R28/Round-9 state (205.8us). R32's
// "container failed twice" was infra: byte-identical source passed at 205.8
// in Round 9 with the same ~56.7MB workspace; Round-12 timing showed acquire
// pathology (148s). No code changes — an edit would confound the retry.
// Falsified-hypothesis ledger for K2 (do not retry): four load-scheduling
// strategies (serial-per-head 48.9 / manual-2-deep 53.4 / compiler-batch 47.4 /
// forced-asm 52.0) all flat -> K2 at its 8-XCD x h1 compulsory-fetch floor
// (~150MB, ~3.2TB/s L3 fill). R31's score-GEMM split + BB=60 regressed +28us
// (builder serial length doubled; GEMM shuffle epilogue was latency-hidden).
// Banked wins: head-merged K2 (R21), two-pass counting-sort build with zero
// global returning atomics (R25; R19-R21: that path caps ~8/ns = 60us floor),
// 10-wide batched prefix + 512-thr builders (R26), all-upfront gather (R28),
// deg<=16/32 uniform fast paths (R26/R27).

typedef _Float16 f16x8 __attribute__((ext_vector_type(8)));
typedef _Float16 f16x2 __attribute__((ext_vector_type(2)));
typedef float fx4 __attribute__((ext_vector_type(4)));

#if defined(__has_builtin)
#if __has_builtin(__builtin_amdgcn_fdot2)
#define HAS_FDOT2 1
#endif
#endif

static __device__ __forceinline__ float leaky(float x) {
    return fmaxf(x, NEG_SLOPE * x); // valid for 0<slope<1
}

// ---------------- barrier-free MFMA fp16 GEMM phase + fused attention scores ----------------
// Wave-slot per 16-row tile (30000 = 16*1875). No LDS, no barriers.
// mfma_f32_16x16x32_f16 layouts (HW-verified): A: lane holds A[m=lane&15][k=quad*8+j];
// B: lane holds B[k=quad*8+j][n=lane&15] (contiguous in Wt[n][k]); D: D[row=quad*4+reg][col=lane&15].
// Scores written NODE-MAJOR with stride SP: as_out[row*SP + h].
template<int NH, int SP, typename AT>
static __device__ __forceinline__ void gemm_phase(const AT* __restrict__ A,
                                                  const __half* __restrict__ Wt,
                                                  __half* __restrict__ C, int K,
                                                  const float* __restrict__ att_src,
                                                  const float* __restrict__ att_dst,
                                                  float* __restrict__ as_out,
                                                  float* __restrict__ ad_out,
                                                  int slot, int nsl, int lane) {
    const int N = NH * 64;
    int q = lane >> 4, l16 = lane & 15;
    for (int tile = slot; tile < N_NODES / 16; tile += nsl) {
        int rowBase = tile * 16;
        int arow = rowBase + l16;
        fx4 zero4 = {0.f, 0.f, 0.f, 0.f};
        fx4 acc[NH][4];
#pragma unroll
        for (int h = 0; h < NH; ++h)
#pragma unroll
            for (int c = 0; c < 4; ++c) acc[h][c] = zero4;
        for (int kk = 0; kk < K; kk += 32) {
            f16x8 af;
            if constexpr (std::is_same<AT, float>::value) {
                const float4* s = (const float4*)(A + (size_t)arow * K + kk + q * 8);
                float4 v0 = s[0], v1 = s[1];
                af[0] = (_Float16)v0.x; af[1] = (_Float16)v0.y;
                af[2] = (_Float16)v0.z; af[3] = (_Float16)v0.w;
                af[4] = (_Float16)v1.x; af[5] = (_Float16)v1.y;
                af[6] = (_Float16)v1.z; af[7] = (_Float16)v1.w;
            } else {
                af = *(const f16x8*)((const __half*)A + (size_t)arow * K + kk + q * 8);
            }
#pragma unroll
            for (int h = 0; h < NH; ++h) {
#pragma unroll
                for (int c = 0; c < 4; ++c) {
                    int col = h * 64 + c * 16 + l16;
                    f16x8 bf = *(const f16x8*)(Wt + (size_t)col * K + kk + q * 8);
                    acc[h][c] = __builtin_amdgcn_mfma_f32_16x16x32_f16(af, bf, acc[h][c], 0, 0, 0);
                }
            }
        }
#pragma unroll
        for (int h = 0; h < NH; ++h) {
            float ps[4] = {0.f, 0.f, 0.f, 0.f};
            float pd[4] = {0.f, 0.f, 0.f, 0.f};
#pragma unroll
            for (int c = 0; c < 4; ++c) {
                int gcol = h * 64 + c * 16 + l16;
                float av = att_src[gcol];
                float dv = att_dst[gcol];
#pragma unroll
                for (int reg = 0; reg < 4; ++reg) {
                    int grow = rowBase + q * 4 + reg;
                    float val = acc[h][c][reg];
                    C[(size_t)grow * N + gcol] = __float2half(val);
                    ps[reg] += val * av;
                    pd[reg] += val * dv;
                }
            }
#pragma unroll
            for (int off = 1; off < 16; off <<= 1) {
#pragma unroll
                for (int reg = 0; reg < 4; ++reg) {
                    ps[reg] += __shfl_xor(ps[reg], off, 64);
                    pd[reg] += __shfl_xor(pd[reg], off, 64);
                }
            }
            if (l16 == 0) {
#pragma unroll
                for (int reg = 0; reg < 4; ++reg) {
                    int grow = rowBase + q * 4 + reg;
                    as_out[(size_t)grow * SP + h] = ps[reg];
                    ad_out[(size_t)grow * SP + h] = pd[reg];
                }
            }
        }
    }
}

// ================ K0 (512-thr): init (self-loops, ovfc, weight transpose) || pass A histogram ================
__global__ __launch_bounds__(512) void k_init(int* __restrict__ ovfc,
                                              int* __restrict__ esrc2,
                                              const float* __restrict__ W1,
                                              __half* __restrict__ Wt1,
                                              const float* __restrict__ W2,
                                              __half* __restrict__ Wt2,
                                              const int* __restrict__ edge,
                                              unsigned* __restrict__ partA) {
    __shared__ unsigned bins[NW]; // 60000 B
    if (blockIdx.x < INIT_BLOCKS) {
        int t = blockIdx.x * 512 + threadIdx.x;
        int nthr = INIT_BLOCKS * 512; // 61440
        for (int i = t; i < N_NODES; i += nthr) esrc2[i * BCAP] = i; // self-loop = slot 0
        if (t == 0) *ovfc = 0;
        const int T1 = IN_CH * D1, T2 = D1 * OUT_CH; // 40960 + 20480 = 61440
        for (int idx = t; idx < T1 + T2; idx += nthr) {
            if (idx < T1) {
                int k = idx / D1, n = idx - k * D1;
                Wt1[(size_t)n * IN_CH + k] = __float2half(W1[idx]);
            } else {
                int i2 = idx - T1;
                int k = i2 / OUT_CH, n = i2 - k * OUT_CH;
                Wt2[(size_t)n * D1 + k] = __float2half(W2[i2]);
            }
        }
    } else {
        int b = blockIdx.x - INIT_BLOCKS; // 0..119
        for (int i = threadIdx.x; i < NW; i += 512) bins[i] = 0;
        __syncthreads();
        int e0 = b * EPB;
        for (int e = e0 + ((int)threadIdx.x << 2); e < e0 + EPB; e += 2048) {
            int4 dd = *(const int4*)(edge + N_EDGES + e);
            atomicAdd(&bins[dd.x >> 1], (dd.x & 1) ? 65536u : 1u);
            atomicAdd(&bins[dd.y >> 1], (dd.y & 1) ? 65536u : 1u);
            atomicAdd(&bins[dd.z >> 1], (dd.z & 1) ? 65536u : 1u);
            atomicAdd(&bins[dd.w >> 1], (dd.w & 1) ? 65536u : 1u);
        }
        __syncthreads();
        for (int i = threadIdx.x; i < NW; i += 512)
            partA[(size_t)b * NW + i] = bins[i];
    }
}

// ================ K1: layer-1 GEMM || prefix over block-partials (10-wide batched) ================
__global__ __launch_bounds__(256) void k_build_gemm1(const unsigned* __restrict__ partA,
                                                     unsigned* __restrict__ offA,
                                                     int* __restrict__ cnt,
                                                     const float* __restrict__ x,
                                                     const __half* __restrict__ Wt1,
                                                     __half* __restrict__ h1,
                                                     const float* __restrict__ att_src1,
                                                     const float* __restrict__ att_dst1,
                                                     float* __restrict__ as1,
                                                     float* __restrict__ ad1) {
    int lane = threadIdx.x & 63, wv = threadIdx.x >> 6;
    if (blockIdx.x < GEMM1_BLOCKS) {
        gemm_phase<HEADS1, 8, float>(x, Wt1, h1, IN_CH, att_src1, att_dst1, as1, ad1,
                                     blockIdx.x * 4 + wv, GEMM1_BLOCKS * 4, lane);
    } else {
        int w = (blockIdx.x - GEMM1_BLOCKS) * 256 + threadIdx.x;
        if (w < NW) {
            unsigned s0 = 1, s1 = 1; // slot 0 = self-loop
            for (int b0 = 0; b0 < BB; b0 += 10) {
                unsigned v[10];
#pragma unroll
                for (int u = 0; u < 10; ++u)
                    v[u] = partA[(size_t)(b0 + u) * NW + w];
#pragma unroll
                for (int u = 0; u < 10; ++u) {
                    offA[(size_t)(b0 + u) * NW + w] = min(s0, 64u) | (min(s1, 64u) << 16);
                    s0 += v[u] & 0xFFFFu;
                    s1 += v[u] >> 16;
                }
            }
            cnt[2 * w] = (int)s0;
            cnt[2 * w + 1] = (int)s1;
        }
    }
}

// ================ K1.5 (512-thr): pass B — rank + scatter (all lanes active) ================
__global__ __launch_bounds__(512) void k_rank(const int* __restrict__ edge,
                                              const unsigned* __restrict__ offA,
                                              int* __restrict__ esrc2,
                                              int* __restrict__ ovf_cnt,
                                              int* __restrict__ ovf) {
    __shared__ unsigned bins[NW];
    int b = blockIdx.x;
    for (int i = threadIdx.x; i < NW; i += 512) bins[i] = 0;
    __syncthreads();
    int e0 = b * EPB;
    for (int e = e0 + ((int)threadIdx.x << 2); e < e0 + EPB; e += 2048) {
        int4 dd = *(const int4*)(edge + N_EDGES + e);
        int4 ss = *(const int4*)(edge + e);
        int dv[4] = {dd.x, dd.y, dd.z, dd.w};
        int sv[4] = {ss.x, ss.y, ss.z, ss.w};
#pragma unroll
        for (int u = 0; u < 4; ++u) {
            int d = dv[u];
            unsigned ret = atomicAdd(&bins[d >> 1], (d & 1) ? 65536u : 1u);
            unsigned lr = (d & 1) ? (ret >> 16) : (ret & 0xFFFFu);
            unsigned off = offA[(size_t)b * NW + (d >> 1)];
            off = (d & 1) ? (off >> 16) : (off & 0xFFFFu);
            unsigned slot = off + lr;
            if (slot < BCAP) {
                esrc2[(d << 6) + slot] = sv[u];
            } else { // true global rank >= 64 (off clamped at 64 keeps this exact)
                int oi = atomicAdd(ovf_cnt, 1);
                if (oi < OVF_CAP) { ovf[2 * oi] = d; ovf[2 * oi + 1] = sv[u]; }
            }
        }
    }
}

// ---------------- R28: all-heads-upfront gather — NH*NS independent loads in flight ----------------
// NS = slots (2 for deg<=16, 4 for deg<=32). All loads issued before any consume;
// single implicit waitcnt; per-head consume + LDS pad-9 epilogue after. Arrays are
// fully-unrolled compile-time indexed (no scratch). Invalid slots carry weight 0.
template<int NH, int NS, bool RELU>
static __device__ __forceinline__ void gather_all(const __half* __restrict__ base, // hf + cg*8
                                                  const unsigned (&wpkw)[NH][64],
                                                  const int (&jbufw)[64],
                                                  float (&redw)[584],
                                                  const float* __restrict__ bias,
                                                  __half* __restrict__ zrow, // zout + node*RS
                                                  int es, int cg, int lane) {
    int kA = es, kB = es + 8, kC = es + 16, kD = es + 24;
    int jA = jbufw[kA], jB = jbufw[kB];
    int jC = (NS == 4) ? jbufw[kC] : 0;
    int jD = (NS == 4) ? jbufw[kD] : 0;
    float4 v[NH][4];
#pragma unroll
    for (int h = 0; h < NH; ++h) {
        const __half* hb = base + h * 64;
        v[h][0] = *(const float4*)(hb + jA);
        v[h][1] = *(const float4*)(hb + jB);
        if (NS == 4) {
            v[h][2] = *(const float4*)(hb + jC);
            v[h][3] = *(const float4*)(hb + jD);
        }
    }
#pragma unroll
    for (int h = 0; h < NH; ++h) {
        unsigned uA = wpkw[h][kA], uB = wpkw[h][kB];
        __half2 hwA = *(__half2*)&uA, hwB = *(__half2*)&uB;
        const __half2* pA = (const __half2*)&v[h][0];
        const __half2* pB = (const __half2*)&v[h][1];
        __half2 a2[4] = {__half2{0, 0}, __half2{0, 0}, __half2{0, 0}, __half2{0, 0}};
#pragma unroll
        for (int i = 0; i < 4; ++i) {
            a2[i] = __hfma2(pA[i], hwA, a2[i]);
            a2[i] = __hfma2(pB[i], hwB, a2[i]);
        }
        if (NS == 4) {
            unsigned uC = wpkw[h][kC], uD = wpkw[h][kD];
            __half2 hwC = *(__half2*)&uC, hwD = *(__half2*)&uD;
            const __half2* pC = (const __half2*)&v[h][2];
            const __half2* pD = (const __half2*)&v[h][3];
#pragma unroll
            for (int i = 0; i < 4; ++i) {
                a2[i] = __hfma2(pC[i], hwC, a2[i]);
                a2[i] = __hfma2(pD[i], hwD, a2[i]);
            }
        }
        // epilogue for head h: fp32 cross-es reduce via LDS pad-9 transpose
#pragma unroll
        for (int i = 0; i < 4; ++i) {
            float2 f = __half22float2(a2[i]);
            redw[(cg * 8 + 2 * i) * 9 + es] = f.x;
            redw[(cg * 8 + 2 * i + 1) * 9 + es] = f.y;
        }
        float tot = 0.f;
#pragma unroll
        for (int e2 = 0; e2 < 8; ++e2)
            tot += redw[lane * 9 + e2];
        float o = tot + bias[h * 64 + lane];
        if (RELU) o = fmaxf(o, 0.f);
        zrow[h * 64 + lane] = __float2half(o);
    }
}

// ================ head-merged softmax + aggregate — ONE WAVE PER NODE ================
// Prologue (R21-proven): one esrc2 gather, all heads' scores via one float4 + scalar
// (node-major [j][SP]), NH pipelined shuffle-reduce trees, weights packed in LDS.
// Gather (R28): deg-uniform 3-way -> all-upfront 2-slot (deg<=16) / 4-slot (deg<=32)
// / legacy serial loop (deg in (32,64], ~0.04% of nodes).
template<int NH, bool RELU>
__global__ __launch_bounds__(256) void k_attn_agg(const int* __restrict__ cnt,
                                                  const int* __restrict__ esrc2,
                                                  const int* __restrict__ ovf_cnt,
                                                  const int* __restrict__ ovf,
                                                  const __half* __restrict__ hf,   // [N][NH*64]
                                                  const float* __restrict__ a_src, // [N][SP]
                                                  const float* __restrict__ a_dst, // [N][SP]
                                                  const float* __restrict__ bias,  // [NH*64]
                                                  __half* __restrict__ zout) {     // [N][NH*64]
    const int SP = (NH == 1) ? 1 : 8;
    __shared__ unsigned wpk[4][NH][64];
    __shared__ int jbuf[4][64];
    __shared__ float red[4][584];
    int node = (blockIdx.x * 256 + threadIdx.x) >> 6;
    int lane = threadIdx.x & 63;
    int wv = threadIdx.x >> 6;
    if (node >= N_NODES) return;
    int deg = cnt[node];
    const int RS = NH * 64;
    // dst-scores for this node (wave-uniform broadcast loads)
    float da[NH];
    if constexpr (NH == 1) {
        da[0] = a_dst[node];
    } else {
        float4 d0 = *(const float4*)(a_dst + (size_t)node * SP);
        da[0] = d0.x; da[1] = d0.y; da[2] = d0.z; da[3] = d0.w;
        da[4] = a_dst[(size_t)node * SP + 4];
    }
    if (deg <= BCAP) {
        int es = lane >> 3, cg = lane & 7;
        int joff = 0;
        float e[NH];
#pragma unroll
        for (int h = 0; h < NH; ++h) e[h] = 0.f;
        if (lane < deg) {
            int j = esrc2[node * BCAP + lane];
            joff = j * RS;
            if constexpr (NH == 1) {
                e[0] = __expf(leaky(a_src[j] + da[0]));
            } else {
                float4 s0 = *(const float4*)(a_src + (size_t)j * SP);
                float s4 = a_src[(size_t)j * SP + 4];
                e[0] = __expf(leaky(s0.x + da[0]));
                e[1] = __expf(leaky(s0.y + da[1]));
                e[2] = __expf(leaky(s0.z + da[2]));
                e[3] = __expf(leaky(s0.w + da[3]));
                e[4] = __expf(leaky(s4 + da[4]));
            }
        }
        float s[NH];
#pragma unroll
        for (int h = 0; h < NH; ++h) s[h] = e[h];
#pragma unroll
        for (int off = 1; off < 64; off <<= 1) {
#pragma unroll
            for (int h = 0; h < NH; ++h) s[h] += __shfl_xor(s[h], off, 64);
        }
#pragma unroll
        for (int h = 0; h < NH; ++h) {
            float r = 1.f / (s[h] + 1e-16f);
            __half2 wn = __float2half2_rn(e[h] * r);
            wpk[wv][h][lane] = *(unsigned*)&wn;
        }
        jbuf[wv][lane] = joff;
        const __half* base = hf + cg * 8;
        __half* zrow = zout + (size_t)node * RS;
        if (deg <= 16) {
            gather_all<NH, 2, RELU>(base, wpk[wv], jbuf[wv], red[wv], bias, zrow, es, cg, lane);
        } else if (deg <= 32) {
            gather_all<NH, 4, RELU>(base, wpk[wv], jbuf[wv], red[wv], bias, zrow, es, cg, lane);
        } else {
            // legacy serial path (deg in (32,64], ~0.04% of nodes)
#pragma unroll
            for (int h = 0; h < NH; ++h) {
                const __half* hbase = hf + h * 64 + cg * 8;
                __half2 acch[4] = {__half2{0, 0}, __half2{0, 0}, __half2{0, 0}, __half2{0, 0}};
                for (int k0 = 0; k0 < deg; k0 += 32) {
                    int kA = k0 + es, kB = kA + 8, kC = kA + 16, kD = kA + 24;
                    unsigned uA = wpk[wv][h][kA];
                    unsigned uB = wpk[wv][h][kB];
                    unsigned uC = wpk[wv][h][kC];
                    unsigned uD = wpk[wv][h][kD];
                    int jA = jbuf[wv][kA];
                    int jB = jbuf[wv][kB];
                    int jC = jbuf[wv][kC];
                    int jD = jbuf[wv][kD];
                    float4 vA = *(const float4*)(hbase + jA);
                    float4 vB = *(const float4*)(hbase + jB);
                    float4 vC = *(const float4*)(hbase + jC);
                    float4 vD = *(const float4*)(hbase + jD);
                    __half2 hwA = *(__half2*)&uA, hwB = *(__half2*)&uB;
                    __half2 hwC = *(__half2*)&uC, hwD = *(__half2*)&uD;
                    const __half2* pA = (const __half2*)&vA;
                    const __half2* pB = (const __half2*)&vB;
                    const __half2* pC = (const __half2*)&vC;
                    const __half2* pD = (const __half2*)&vD;
#pragma unroll
                    for (int i = 0; i < 4; ++i) {
                        acch[i] = __hfma2(pA[i], hwA, acch[i]);
                        acch[i] = __hfma2(pB[i], hwB, acch[i]);
                        acch[i] = __hfma2(pC[i], hwC, acch[i]);
                        acch[i] = __hfma2(pD[i], hwD, acch[i]);
                    }
                }
#pragma unroll
                for (int i = 0; i < 4; ++i) {
                    float2 f = __half22float2(acch[i]);
                    red[wv][(cg * 8 + 2 * i) * 9 + es] = f.x;
                    red[wv][(cg * 8 + 2 * i + 1) * 9 + es] = f.y;
                }
                float tot = 0.f;
#pragma unroll
                for (int e2 = 0; e2 < 8; ++e2)
                    tot += red[wv][lane * 9 + e2];
                float o = tot + bias[h * 64 + lane];
                if (RELU) o = fmaxf(o, 0.f);
                zrow[h * 64 + lane] = __float2half(o);
            }
        }
    } else {
        // cold path: deg > BCAP. lane = channel; bucket (64 full) + overflow scan.
        int ovn = min(*ovf_cnt, OVF_CAP);
#pragma unroll
        for (int h = 0; h < NH; ++h) {
            float adsth = da[h];
            float sden = __expf(leaky(a_src[(size_t)esrc2[node * BCAP + lane] * SP + h] + adsth));
#pragma unroll
            for (int off = 1; off < 64; off <<= 1)
                sden += __shfl_xor(sden, off, 64);
            float s2 = 0.f;
            for (int k = lane; k < ovn; k += 64)
                if (ovf[2 * k] == node)
                    s2 += __expf(leaky(a_src[(size_t)ovf[2 * k + 1] * SP + h] + adsth));
#pragma unroll
            for (int off = 1; off < 64; off <<= 1)
                s2 += __shfl_xor(s2, off, 64);
            float r = 1.f / (sden + s2 + 1e-16f);
            float a = 0.f;
            for (int k = 0; k < BCAP; ++k) {
                int j = esrc2[node * BCAP + k];
                float w = __expf(leaky(a_src[(size_t)j * SP + h] + adsth));
                a += w * __half2float(hf[(size_t)j * RS + h * 64 + lane]);
            }
            for (int k = 0; k < ovn; ++k) {
                if (ovf[2 * k] == node) {
                    int j = ovf[2 * k + 1];
                    float w = __expf(leaky(a_src[(size_t)j * SP + h] + adsth));
                    a += w * __half2float(hf[(size_t)j * RS + h * 64 + lane]);
                }
            }
            float o = a * r + bias[h * 64 + lane];
            if (RELU) o = fmaxf(o, 0.f);
            zout[(size_t)node * RS + h * 64 + lane] = __float2half(o);
        }
    }
}

// ================ layer-2 GEMM (slot-strided, 256-thr blocks) ================
__global__ __launch_bounds__(256) void k_gemm2(const __half* __restrict__ z1,
                                               const __half* __restrict__ Wt2,
                                               __half* __restrict__ h2,
                                               const float* __restrict__ att_src2,
                                               const float* __restrict__ att_dst2,
                                               float* __restrict__ as2,
                                               float* __restrict__ ad2) {
    int lane = threadIdx.x & 63, wv = threadIdx.x >> 6;
    gemm_phase<1, 1, __half>(z1, Wt2, h2, D1, att_src2, att_dst2, as2, ad2,
                             blockIdx.x * 4 + wv, gridDim.x * 4, lane);
}

// ================ decode: 8 lanes per edge, 16B fp16 loads, fdot2 ================
__global__ __launch_bounds__(256) void k_decode(const int* __restrict__ pos,
                                                const int* __restrict__ neg,
                                                const __half* __restrict__ z2,
                                                float* __restrict__ out) {
    int t = blockIdx.x * 256 + threadIdx.x;
    int e = t >> 3;
    int lc = t & 7;
    if (e >= 2 * PE_CNT) return;
    int a, b;
    if (e < PE_CNT) { a = pos[e]; b = pos[PE_CNT + e]; }
    else { int k = e - PE_CNT; a = neg[k]; b = neg[PE_CNT + k]; }
    union U { float4 f; f16x2 h[4]; __half2 hh[4]; } ua, ub;
    ua.f = *(const float4*)(z2 + (size_t)a * OUT_CH + lc * 8);
    ub.f = *(const float4*)(z2 + (size_t)b * OUT_CH + lc * 8);
    float v = 0.f;
#pragma unroll
    for (int i = 0; i < 4; ++i) {
#ifdef HAS_FDOT2
        v = __builtin_amdgcn_fdot2(ua.h[i], ub.h[i], v, false);
#else
        float2 fa = __half22float2(ua.hh[i]);
        float2 fb = __half22float2(ub.hh[i]);
        v += fa.x * fb.x + fa.y * fb.y;
#endif
    }
#pragma unroll
    for (int off = 1; off < 8; off <<= 1)
        v += __shfl_xor(v, off, 64);
    if (lc == 0) out[e] = v;
}

extern "C" void kernel_launch(void* const* d_in, const int* in_sizes, int n_in,
                              void* d_out, int out_size, void* d_ws, size_t ws_size,
                              hipStream_t stream) {
    const float* x        = (const float*)d_in[0];
    const int* edge_index = (const int*)d_in[1];
    const int* pos_ei     = (const int*)d_in[2];
    const int* neg_ei     = (const int*)d_in[3];
    const float* W1       = (const float*)d_in[4];
    const float* att_src1 = (const float*)d_in[5];
    const float* att_dst1 = (const float*)d_in[6];
    const float* b1       = (const float*)d_in[7];
    const float* W2       = (const float*)d_in[8];
    const float* att_src2 = (const float*)d_in[9];
    const float* att_dst2 = (const float*)d_in[10];
    const float* b2       = (const float*)d_in[11];
    float* out            = (float*)d_out;

    char* ws = (char*)d_ws;
    size_t off = 0;
    auto alloc = [&](size_t bytes) -> void* {
        void* p = ws + off;
        off = (off + bytes + 255) & ~(size_t)255;
        return p;
    };
    int* cnt     = (int*)alloc(sizeof(int) * N_NODES);
    int* ovfc    = (int*)alloc(sizeof(int) * 8);
    int* esrc2   = (int*)alloc(sizeof(int) * (size_t)N_NODES * BCAP);
    int* ovf     = (int*)alloc(sizeof(int) * (size_t)2 * OVF_CAP); // 512KB capped
    __half* h1   = (__half*)alloc(sizeof(__half) * (size_t)N_NODES * D1);
    __half* z1   = (__half*)alloc(sizeof(__half) * (size_t)N_NODES * D1);
    __half* h2   = (__half*)alloc(sizeof(__half) * (size_t)N_NODES * OUT_CH);
    __half* z2   = (__half*)alloc(sizeof(__half) * (size_t)N_NODES * OUT_CH);
    __half* Wt1  = (__half*)alloc(sizeof(__half) * (size_t)D1 * IN_CH);
    __half* Wt2  = (__half*)alloc(sizeof(__half) * (size_t)OUT_CH * D1);
    float* as1   = (float*)alloc(sizeof(float) * (size_t)N_NODES * 8); // [N][8] node-major, 5 used
    float* ad1   = (float*)alloc(sizeof(float) * (size_t)N_NODES * 8); // [N][8]
    float* as2   = (float*)alloc(sizeof(float) * (size_t)N_NODES);
    float* ad2   = (float*)alloc(sizeof(float) * (size_t)N_NODES);
    // partA/offA (7.2MB each) ALIAS z1's 19.2MB: both are dead after k_rank,
    // and z1 is first written in K2 which stream-orders after k_rank. 256-aligned
    // (7,200,000 % 256 == 0). Keeps total ws ~56.7MB (R24's separate allocations
    // hit 74.6MB and crashed the ~64MB workspace).
    unsigned* partA = (unsigned*)z1;
    unsigned* offA  = (unsigned*)((char*)z1 + (size_t)BB * NW * sizeof(unsigned));

    // K0: init (self-loops, ovfc, weight prep) || pass A (LDS histogram -> partA)
    k_init<<<INIT_BLOCKS + BB, 512, 0, stream>>>(ovfc, esrc2, W1, Wt1, W2, Wt2,
                                                 edge_index, partA);
    // K1: layer-1 MFMA GEMM + scores || prefix (partA -> offA, cnt)
    k_build_gemm1<<<GEMM1_BLOCKS + PFX_BLOCKS, 256, 0, stream>>>(
        partA, offA, cnt, x, Wt1, h1, att_src1, att_dst1, as1, ad1);
    // K1.5: pass B — rank assignment + esrc2 scatter
    k_rank<<<BB, 512, 0, stream>>>(edge_index, offA, esrc2, ovfc, ovf);
    // K2: layer-1 softmax-aggregate (+relu) — one wave per node, 5 heads merged
    k_attn_agg<HEADS1, true><<<(N_NODES + 3) / 4, 256, 0, stream>>>(
        cnt, esrc2, ovfc, ovf, h1, as1, ad1, b1, z1);
    // K3: layer-2 GEMM + scores
    k_gemm2<<<469, 256, 0, stream>>>(z1, Wt2, h2, att_src2, att_dst2, as2, ad2);
    // K4: layer-2 softmax-aggregate
    k_attn_agg<1, false><<<(N_NODES + 3) / 4, 256, 0, stream>>>(
        cnt, esrc2, ovfc, ovf, h2, as2, ad2, b2, z2);
    // K5: decode
    k_decode<<<(2 * PE_CNT * 8 + 255) / 256, 256, 0, stream>>>(pos_ei, neg_ei, z2, out);

    (void)in_sizes; (void)n_in; (void)out_size; (void)ws_size;
}